// Round 8
// baseline (534.457 us; speedup 1.0000x reference)
//
#include <hip/hip_runtime.h>
#include <hip/hip_bf16.h>
#include <math.h>

#define B_   16
#define T_   4096
#define KD_  1024
#define AD_  512
#define VD_  1024

typedef float f32x4 __attribute__((ext_vector_type(4)));
typedef short s16x8 __attribute__((ext_vector_type(8)));

static __device__ __forceinline__ short f2bf(float f) {
    __hip_bfloat16 h = __float2bfloat16(f);
    return __builtin_bit_cast(short, h);
}

static __device__ __forceinline__ float fast_tanh(float x) {
    x = fminf(fmaxf(x, -15.f), 15.f);
    float e = __expf(2.f * x);
    return (e - 1.f) / (e + 1.f);
}

static __device__ __forceinline__ void gload16(const void* g, void* l) {
    __builtin_amdgcn_global_load_lds(
        (const __attribute__((address_space(1))) void*)(g),
        (__attribute__((address_space(3))) void*)(l), 16, 0, 0);
}

// A (f32, direct from key): LDS slots of 16B (4 floats). Row r (0..127) x sub (0..7).
//   LDS slot (r<<3)|ss holds global data-sub ss^(r&7)  [source-side permutation, rule #21]
//   Read of data-sub s for row r -> slot (r<<3)|(s^(r&7)): 16 rows spread over all 32 banks, 2-way.
// B (bf16, pre-baked blocked WkTB): [ntile128][kt][chunk c(512)][8 bf16], c=(r<<2)|(sub^((r>>1)&3)).

// ---------------- kernel 1: qb[mat][b][a] = b_bias[a] + query[b,:]·Wq[:,a] ----------------
__global__ __launch_bounds__(256) void qproj_kernel(
    const float* __restrict__ query,
    const float* __restrict__ Wq_mono, const float* __restrict__ b_mono,
    const float* __restrict__ Wq_chunk, const float* __restrict__ b_chunk,
    float* __restrict__ qb) {
    __shared__ float red[4][64];
    int b = blockIdx.x;       // 0..15
    int mat = blockIdx.y;     // 0..1
    int ac = blockIdx.z;      // 0..7 (64-wide a chunk)
    const float* Wq = mat ? Wq_chunk : Wq_mono;
    const float* bb = mat ? b_chunk : b_mono;
    int al = threadIdx.x & 63;
    int dg = threadIdx.x >> 6;       // 0..3, 256 d's each
    int a = ac * 64 + al;
    const float* q = query + b * KD_ + dg * 256;
    const float* wp = Wq + (size_t)(dg * 256) * AD_ + a;
    float s = 0.f;
#pragma unroll 4
    for (int d = 0; d < 256; ++d)
        s += q[d] * wp[(size_t)d * AD_];
    red[dg][al] = s;
    __syncthreads();
    if (dg == 0) {
        float t = red[0][al] + red[1][al] + red[2][al] + red[3][al];
        qb[(mat * B_ + b) * AD_ + a] = t + bb[a];
    }
}

// ---------------- kernel 2: weights -> bf16 blocked+swizzled WkTB ----------------
__global__ __launch_bounds__(256) void wtrans_kernel(
    const float* __restrict__ Wk_mono, const float* __restrict__ Wk_chunk,
    short* __restrict__ WkTB) {
    __shared__ float tile[32][33];
    int n0 = blockIdx.x * 32;    // combined col (0..1023): n<512 mono, else chunk
    int k0 = blockIdx.y * 32;    // row (0..1023)
    int tx = threadIdx.x;        // 0..31
    int ty = threadIdx.y;        // 0..7
    int tid = ty * 32 + tx;
    const float* src;
    int nloc;
    if (n0 < 512) { src = Wk_mono;  nloc = n0; }
    else          { src = Wk_chunk; nloc = n0 - 512; }
#pragma unroll
    for (int i = 0; i < 4; ++i) {
        int k = ty + i * 8;
        tile[k][tx] = src[(size_t)(k0 + k) * AD_ + nloc + tx];   // tile[k_local][n_local]
    }
    __syncthreads();
    if (tid < 128) {
        int r = tid >> 2;       // local n (0..31)
        int sub = tid & 3;      // k-chunk within 32
        s16x8 h;
#pragma unroll
        for (int j = 0; j < 8; ++j)
            h[j] = f2bf(tile[sub * 8 + j][r]);
        int n = n0 + r;
        int nblk = n >> 7;
        int rloc = n & 127;
        int kt = k0 >> 5;
        int c = (rloc << 2) | (sub ^ ((rloc >> 1) & 3));   // bank swizzle
        *reinterpret_cast<s16x8*>(WkTB + (((size_t)(nblk * 32 + kt) * 512 + c) << 3)) = h;
    }
}

// ---------------- kernel 3: fused GEMM 128x128, f32-A DMA-staged (no cvt pass), 2-phase dbuf ----------------
__global__ __launch_bounds__(256) void gemm_e_kernel(
    const float* __restrict__ key,
    const short* __restrict__ WkTB,
    const float* __restrict__ qb,
    const float* __restrict__ v_mono, const float* __restrict__ v_chunk,
    float* __restrict__ e_ws /* [2][B_*T_] */) {
    __shared__ float Asf[2][128 * 32];   // 32 KB: f32 A, dbuf, swizzled 16B slots
    __shared__ short Bs[2][128 * 32];    // 16 KB: bf16 B, dbuf
    int tid = threadIdx.x;
    int bid = blockIdx.x;
    int swz = (bid & 7) * 512 + (bid >> 3);   // XCD-aware (4096 % 8 == 0, bijective)
    int mt = swz >> 3;
    int nt = swz & 7;
    int mBase = mt * 128;
    int nBase = nt * 128;
    int lane = tid & 63;
    int wid = tid >> 6;
    int wr = wid >> 1, wc = wid & 1;
    int col16 = lane & 15, g4 = lane >> 4;

    // --- A staging: 1024 chunks (16B = 4 floats); thread stages 4: c = i*256 + tid ---
    const float* pA[4];
    int sAf[4];
#pragma unroll
    for (int i = 0; i < 4; ++i) {
        int c = i * 256 + tid;
        int r = c >> 3;
        int ss = c & 7;
        int sd = ss ^ (r & 7);                 // source-side swizzle
        pA[i] = key + (size_t)(mBase + r) * KD_ + sd * 4;   // += 32 per K-step
        sAf[i] = (i * 256 + wid * 64) * 16;    // LDS float-offset... (chunks*4 floats)
    }
    // NOTE: sAf holds float offsets: chunk base (i*256+wid*64) chunks * 4 floats each
#pragma unroll
    for (int i = 0; i < 4; ++i) sAf[i] = (i * 256 + wid * 64) * 4;

    // --- B staging (blocked+swizzled global, linear LDS dest) ---
    int cB0 = wid * 128 + lane;
    int cB1 = cB0 + 64;
    const short* pB0 = WkTB + (((size_t)nt * 32) * 512 + cB0) * 8;
    const short* pB1 = WkTB + (((size_t)nt * 32) * 512 + cB1) * 8;
    int sB0 = (wid * 128 + 0) * 8;
    int sB1 = (wid * 128 + 64) * 8;

    // loop-invariant swizzled ds_read offsets
    int aoff0[4], aoff1[4];   // float offsets (two 16B slots per frag)
    int boff[4];              // short offsets
#pragma unroll
    for (int m = 0; m < 4; ++m) {
        int row = wr * 64 + m * 16 + col16;
        aoff0[m] = (row * 8 + ((g4 * 2)     ^ (row & 7))) * 4;
        aoff1[m] = (row * 8 + ((g4 * 2 + 1) ^ (row & 7))) * 4;
    }
#pragma unroll
    for (int n = 0; n < 4; ++n) {
        int row = wc * 64 + n * 16 + col16;
        boff[n] = (row * 4 + (g4 ^ ((row >> 1) & 3))) * 8;
    }

    f32x4 zero4 = {0.f, 0.f, 0.f, 0.f};
    f32x4 acc[4][4];
#pragma unroll
    for (int m = 0; m < 4; ++m)
#pragma unroll
        for (int n = 0; n < 4; ++n) acc[m][n] = zero4;

    // prologue: stage tile 0 into buf 0
#pragma unroll
    for (int i = 0; i < 4; ++i) gload16(pA[i], &Asf[0][sAf[i]]);
    gload16(pB0, &Bs[0][sB0]);
    gload16(pB1, &Bs[0][sB1]);
#pragma unroll
    for (int i = 0; i < 4; ++i) pA[i] += 32;
    pB0 += 4096; pB1 += 4096;
    __syncthreads();

    int cur = 0;
    for (int kt = 0; kt < 31; ++kt) {
        int nxt = cur ^ 1;
        // prefetch next tile (overlaps with MFMA; drained by the barrier)
#pragma unroll
        for (int i = 0; i < 4; ++i) gload16(pA[i], &Asf[nxt][sAf[i]]);
        gload16(pB0, &Bs[nxt][sB0]);
        gload16(pB1, &Bs[nxt][sB1]);
#pragma unroll
        for (int i = 0; i < 4; ++i) pA[i] += 32;
        pB0 += 4096; pB1 += 4096;
        // compute current tile: read f32 A, convert to bf16 fragments
        s16x8 af[4], bfr[4];
#pragma unroll
        for (int m = 0; m < 4; ++m) {
            f32x4 a0 = *reinterpret_cast<const f32x4*>(&Asf[cur][aoff0[m]]);
            f32x4 a1 = *reinterpret_cast<const f32x4*>(&Asf[cur][aoff1[m]]);
            s16x8 h;
            h[0] = f2bf(a0[0]); h[1] = f2bf(a0[1]); h[2] = f2bf(a0[2]); h[3] = f2bf(a0[3]);
            h[4] = f2bf(a1[0]); h[5] = f2bf(a1[1]); h[6] = f2bf(a1[2]); h[7] = f2bf(a1[3]);
            af[m] = h;
        }
#pragma unroll
        for (int n = 0; n < 4; ++n)
            bfr[n] = *reinterpret_cast<const s16x8*>(&Bs[cur][boff[n]]);
#pragma unroll
        for (int m = 0; m < 4; ++m)
#pragma unroll
            for (int n = 0; n < 4; ++n)
                acc[m][n] = __builtin_amdgcn_mfma_f32_16x16x32_bf16(af[m], bfr[n], acc[m][n], 0, 0, 0);
        __syncthreads();   // vmcnt drain: next buffer published, cur free
        cur = nxt;
    }
    {   // final tile
        s16x8 af[4], bfr[4];
#pragma unroll
        for (int m = 0; m < 4; ++m) {
            f32x4 a0 = *reinterpret_cast<const f32x4*>(&Asf[cur][aoff0[m]]);
            f32x4 a1 = *reinterpret_cast<const f32x4*>(&Asf[cur][aoff1[m]]);
            s16x8 h;
            h[0] = f2bf(a0[0]); h[1] = f2bf(a0[1]); h[2] = f2bf(a0[2]); h[3] = f2bf(a0[3]);
            h[4] = f2bf(a1[0]); h[5] = f2bf(a1[1]); h[6] = f2bf(a1[2]); h[7] = f2bf(a1[3]);
            af[m] = h;
        }
#pragma unroll
        for (int n = 0; n < 4; ++n)
            bfr[n] = *reinterpret_cast<const s16x8*>(&Bs[cur][boff[n]]);
#pragma unroll
        for (int m = 0; m < 4; ++m)
#pragma unroll
            for (int n = 0; n < 4; ++n)
                acc[m][n] = __builtin_amdgcn_mfma_f32_16x16x32_bf16(af[m], bfr[n], acc[m][n], 0, 0, 0);
    }

    // epilogue: e[row] += sum_a v[a] * tanh(C[row][a] + qb[b][a])
    int bIdx = mBase >> 12;             // token row / 4096
    int matrix = nBase >> 9;            // 0=mono, 1=chunk
    int aBase = (nBase & 511) + wc * 64 + col16;
    const float* qbRow = qb + (matrix * B_ + bIdx) * AD_;
    const float* vv = matrix ? v_chunk : v_mono;
    float* eArr = e_ws + matrix * (B_ * T_);
    float qcol[4], vcol[4];
#pragma unroll
    for (int n = 0; n < 4; ++n) {
        int a = aBase + n * 16;
        qcol[n] = qbRow[a];
        vcol[n] = vv[a];
    }
#pragma unroll
    for (int m = 0; m < 4; ++m) {
        float s0 = 0.f, s1 = 0.f, s2 = 0.f, s3 = 0.f;
#pragma unroll
        for (int n = 0; n < 4; ++n) {
            s0 += fast_tanh(acc[m][n][0] + qcol[n]) * vcol[n];
            s1 += fast_tanh(acc[m][n][1] + qcol[n]) * vcol[n];
            s2 += fast_tanh(acc[m][n][2] + qcol[n]) * vcol[n];
            s3 += fast_tanh(acc[m][n][3] + qcol[n]) * vcol[n];
        }
#pragma unroll
        for (int mask = 1; mask < 16; mask <<= 1) {
            s0 += __shfl_xor(s0, mask, 64);
            s1 += __shfl_xor(s1, mask, 64);
            s2 += __shfl_xor(s2, mask, 64);
            s3 += __shfl_xor(s3, mask, 64);
        }
        if (col16 == 0) {
            int rowB = mBase + wr * 64 + m * 16 + g4 * 4;
            atomicAdd(&eArr[rowB + 0], s0);
            atomicAdd(&eArr[rowB + 1], s1);
            atomicAdd(&eArr[rowB + 2], s2);
            atomicAdd(&eArr[rowB + 3], s3);
        }
    }
}

// ---------------- kernel 4: per-batch scan -> aw, beta ----------------
__global__ __launch_bounds__(256) void scan_kernel(
    const float* __restrict__ e_ws,
    const float* __restrict__ noise,
    const float* __restrict__ r_mono, const float* __restrict__ r_chunk,
    float* __restrict__ aw_out, float* __restrict__ beta_out) {
    __shared__ float s_aw[T_];
    __shared__ float s_sexp[T_];
    __shared__ float s_ad[T_];
    __shared__ float s_w[4];
    int b = blockIdx.x;
    int tid = threadIdx.x;
    int lane = tid & 63;
    int wid4 = tid >> 6;
    int t0 = tid * 16;
    const float* em = e_ws + b * T_;
    const float* ec = e_ws + B_ * T_ + b * T_;
    const float* nz = noise + b * T_;
    float rm = r_mono[0], rc = r_chunk[0];

    float pv[16], lp[16];
    float run = 0.f;
#pragma unroll
    for (int j = 0; j < 16; ++j) {
        float x = em[t0 + j] + rm + nz[t0 + j];
        float p = 1.f / (1.f + expf(-x));
        pv[j] = p;
        float om = fminf(fmaxf(1.f - p, 1e-10f), 1.f);
        lp[j] = run;
        run += logf(om);
    }
    float x = run;
#pragma unroll
    for (int off = 1; off < 64; off <<= 1) {
        float y = __shfl_up(x, off, 64);
        if (lane >= off) x += y;
    }
    if (lane == 63) s_w[wid4] = x;
    __syncthreads();
    float wbase = 0.f;
#pragma unroll
    for (int i = 0; i < 3; ++i) if (i < wid4) wbase += s_w[i];
    float base = 1.f + (wbase + x - run);
#pragma unroll
    for (int j = 0; j < 16; ++j) {
        float aw = pv[j] * expf(base + lp[j]);
        s_aw[t0 + j] = aw;
        aw_out[b * T_ + t0 + j] = aw;
    }
    float evs[16];
    float lmax = -INFINITY;
#pragma unroll
    for (int j = 0; j < 16; ++j) {
        float v = ec[t0 + j] + rc;
        evs[j] = v;
        lmax = fmaxf(lmax, v);
    }
#pragma unroll
    for (int off = 1; off < 64; off <<= 1)
        lmax = fmaxf(lmax, __shfl_xor(lmax, off, 64));
    __syncthreads();
    if (lane == 0) s_w[wid4] = lmax;
    __syncthreads();
    float mx = fmaxf(fmaxf(s_w[0], s_w[1]), fmaxf(s_w[2], s_w[3]));
#pragma unroll
    for (int j = 0; j < 16; ++j)
        s_sexp[t0 + j] = fmaxf(expf(evs[j] - mx), 1e-5f);
    __syncthreads();
#pragma unroll
    for (int j = 0; j < 16; ++j) {
        int t = t0 + j;
        int lo = t - 7; if (lo < 0) lo = 0;
        float d = 0.f;
        for (int i = lo; i <= t; ++i) d += s_sexp[i];
        s_ad[t] = s_aw[t] / d;
    }
    __syncthreads();
#pragma unroll
    for (int j = 0; j < 16; ++j) {
        int t = t0 + j;
        int hi = t + 7; if (hi > T_ - 1) hi = T_ - 1;
        float m2 = 0.f;
        for (int i = t; i <= hi; ++i) m2 += s_ad[i];
        beta_out[b * T_ + t] = s_sexp[t] * m2;
    }
}

// ---------------- kernel 5: cv[b][d] = sum_t beta[b][t]*value[b][t][d] ----------------
__global__ __launch_bounds__(256) void cv_kernel(
    const float* __restrict__ value,
    const float* __restrict__ beta,
    float* __restrict__ cv) {
    __shared__ float s_beta[128];
    int b = blockIdx.x;
    int tc = blockIdx.y;
    int tid = threadIdx.x;
    int t0 = tc * 128;
    if (tid < 128) s_beta[tid] = beta[b * T_ + t0 + tid];
    __syncthreads();
    int d0 = tid * 4;
    f32x4 acc = {0.f, 0.f, 0.f, 0.f};
    const float* vp = value + (size_t)(b * T_ + t0) * VD_ + d0;
#pragma unroll 4
    for (int i = 0; i < 128; ++i) {
        f32x4 v = *reinterpret_cast<const f32x4*>(vp + (size_t)i * VD_);
        float bt = s_beta[i];
        acc[0] += bt * v[0];
        acc[1] += bt * v[1];
        acc[2] += bt * v[2];
        acc[3] += bt * v[3];
    }
    atomicAdd(&cv[b * VD_ + d0 + 0], acc[0]);
    atomicAdd(&cv[b * VD_ + d0 + 1], acc[1]);
    atomicAdd(&cv[b * VD_ + d0 + 2], acc[2]);
    atomicAdd(&cv[b * VD_ + d0 + 3], acc[3]);
}

extern "C" void kernel_launch(void* const* d_in, const int* in_sizes, int n_in,
                              void* d_out, int out_size, void* d_ws, size_t ws_size,
                              hipStream_t stream) {
    const float* key      = (const float*)d_in[0];
    const float* value    = (const float*)d_in[1];
    const float* query    = (const float*)d_in[2];
    const float* noise    = (const float*)d_in[3];
    const float* Wk_mono  = (const float*)d_in[4];
    const float* b_mono   = (const float*)d_in[5];
    const float* Wq_mono  = (const float*)d_in[6];
    const float* Wk_chunk = (const float*)d_in[7];
    const float* b_chunk  = (const float*)d_in[8];
    const float* Wq_chunk = (const float*)d_in[9];
    const float* r_mono   = (const float*)d_in[10];
    const float* r_chunk  = (const float*)d_in[11];
    const float* v_mono   = (const float*)d_in[12];
    const float* v_chunk  = (const float*)d_in[13];
    float* out = (float*)d_out;   // [0,16384): cv ; [16384, 81920): aw

    char* ws = (char*)d_ws;
    size_t off = 0;
    float* e_ws = (float*)(ws + off); off += 2 * B_ * T_ * sizeof(float);      // 512 KB
    float* qb   = (float*)(ws + off); off += 2 * B_ * AD_ * sizeof(float);     // 64 KB
    short* WkTB = (short*)(ws + off); off += (size_t)KD_ * KD_ * 2;            // 2 MB (blocked+swizzled)
    float* beta = (float*)(ws + off); off += B_ * T_ * sizeof(float);          // 256 KB

    hipMemsetAsync(e_ws, 0, 2 * B_ * T_ * sizeof(float), stream);
    hipMemsetAsync(out, 0, B_ * VD_ * sizeof(float), stream);

    qproj_kernel<<<dim3(16, 2, 8), 256, 0, stream>>>(query, Wq_mono, b_mono, Wq_chunk, b_chunk, qb);
    wtrans_kernel<<<dim3(32, 32), dim3(32, 8), 0, stream>>>(Wk_mono, Wk_chunk, WkTB);
    gemm_e_kernel<<<4096, 256, 0, stream>>>(key, WkTB, qb, v_mono, v_chunk, e_ws);
    scan_kernel<<<16, 256, 0, stream>>>(e_ws, noise, r_mono, r_chunk, out + B_ * VD_, beta);
    cv_kernel<<<dim3(16, 32), 256, 0, stream>>>(value, beta, out);
}

// Round 9
// 376.899 us; speedup vs baseline: 1.4180x; 1.4180x over previous
//
#include <hip/hip_runtime.h>
#include <hip/hip_bf16.h>
#include <math.h>

#define B_   16
#define T_   4096
#define KD_  1024
#define AD_  512
#define VD_  1024

typedef float f32x4 __attribute__((ext_vector_type(4)));
typedef short s16x8 __attribute__((ext_vector_type(8)));

static __device__ __forceinline__ short f2bf(float f) {
    __hip_bfloat16 h = __float2bfloat16(f);
    return __builtin_bit_cast(short, h);
}

static __device__ __forceinline__ float fast_tanh(float x) {
    x = fminf(fmaxf(x, -15.f), 15.f);
    float e = __expf(2.f * x);
    return (e - 1.f) / (e + 1.f);
}

static __device__ __forceinline__ void gload16(const void* g, void* l) {
    __builtin_amdgcn_global_load_lds(
        (const __attribute__((address_space(1))) void*)(g),
        (__attribute__((address_space(3))) void*)(l), 16, 0, 0);
}

// Blocked operand layouts (16B chunks, bank-swizzled slots), both 256-row tiles:
//   A (keyB): [mtile256][kt(K/32)][chunk c(1024)][8 bf16], c = (r<<2)|(sub^((r>>1)&3)), r=0..255
//   B (WkTB): [ntile256][kt(K/32)][chunk c(1024)][8 bf16], same c formula
// LDS stays linear (global_load_lds); ds_read applies the same XOR -> 2-way (free, r6-verified).

// ---------------- kernel 0: key f32 -> bf16, blocked+swizzled (256-row tiles) ----------------
__global__ __launch_bounds__(256) void cvt_key_blk_kernel(
    const float* __restrict__ key, short* __restrict__ keyB) {
    const size_t nchunk = (size_t)B_ * T_ * KD_ / 8;
    size_t stride = (size_t)gridDim.x * 256;
    for (size_t g = (size_t)blockIdx.x * 256 + threadIdx.x; g < nchunk; g += stride) {
        const float* p = key + g * 8;          // contiguous read
        f32x4 f0 = *reinterpret_cast<const f32x4*>(p);
        f32x4 f1 = *reinterpret_cast<const f32x4*>(p + 4);
        s16x8 h;
        h[0] = f2bf(f0[0]); h[1] = f2bf(f0[1]); h[2] = f2bf(f0[2]); h[3] = f2bf(f0[3]);
        h[4] = f2bf(f1[0]); h[5] = f2bf(f1[1]); h[6] = f2bf(f1[2]); h[7] = f2bf(f1[3]);
        size_t m = g >> 7;
        int kc = (int)(g & 127);
        size_t mt = m >> 8;                    // 256-row tiles
        int r = (int)(m & 255);
        int kt = kc >> 2;
        int sub = kc & 3;
        int c = (r << 2) | (sub ^ ((r >> 1) & 3));   // bank swizzle
        *reinterpret_cast<s16x8*>(keyB + (((mt * 32 + kt) * 1024 + c) << 3)) = h;
    }
}

// ---------------- kernel 1: qb[mat][b][a] = b_bias[a] + query[b,:]·Wq[:,a] ----------------
__global__ __launch_bounds__(256) void qproj_kernel(
    const float* __restrict__ query,
    const float* __restrict__ Wq_mono, const float* __restrict__ b_mono,
    const float* __restrict__ Wq_chunk, const float* __restrict__ b_chunk,
    float* __restrict__ qb) {
    __shared__ float red[4][64];
    int b = blockIdx.x;       // 0..15
    int mat = blockIdx.y;     // 0..1
    int ac = blockIdx.z;      // 0..7 (64-wide a chunk)
    const float* Wq = mat ? Wq_chunk : Wq_mono;
    const float* bb = mat ? b_chunk : b_mono;
    int al = threadIdx.x & 63;
    int dg = threadIdx.x >> 6;       // 0..3, 256 d's each
    int a = ac * 64 + al;
    const float* q = query + b * KD_ + dg * 256;
    const float* wp = Wq + (size_t)(dg * 256) * AD_ + a;
    float s = 0.f;
#pragma unroll 4
    for (int d = 0; d < 256; ++d)
        s += q[d] * wp[(size_t)d * AD_];
    red[dg][al] = s;
    __syncthreads();
    if (dg == 0) {
        float t = red[0][al] + red[1][al] + red[2][al] + red[3][al];
        qb[(mat * B_ + b) * AD_ + a] = t + bb[a];
    }
}

// ---------------- kernel 2: weights -> bf16 blocked+swizzled WkTB (256-col tiles) ----------------
__global__ __launch_bounds__(256) void wtrans_kernel(
    const float* __restrict__ Wk_mono, const float* __restrict__ Wk_chunk,
    short* __restrict__ WkTB) {
    __shared__ float tile[32][33];
    int n0 = blockIdx.x * 32;    // combined col (0..1023): n<512 mono, else chunk
    int k0 = blockIdx.y * 32;    // row (0..1023)
    int tx = threadIdx.x;        // 0..31
    int ty = threadIdx.y;        // 0..7
    int tid = ty * 32 + tx;
    const float* src;
    int nloc;
    if (n0 < 512) { src = Wk_mono;  nloc = n0; }
    else          { src = Wk_chunk; nloc = n0 - 512; }
#pragma unroll
    for (int i = 0; i < 4; ++i) {
        int k = ty + i * 8;
        tile[k][tx] = src[(size_t)(k0 + k) * AD_ + nloc + tx];   // tile[k_local][n_local]
    }
    __syncthreads();
    if (tid < 128) {
        int r = tid >> 2;       // local n (0..31)
        int sub = tid & 3;      // k-chunk within 32
        s16x8 h;
#pragma unroll
        for (int j = 0; j < 8; ++j)
            h[j] = f2bf(tile[sub * 8 + j][r]);
        int n = n0 + r;
        int nblk = n >> 8;      // 256-col tiles
        int rloc = n & 255;
        int kt = k0 >> 5;
        int c = (rloc << 2) | (sub ^ ((rloc >> 1) & 3));   // bank swizzle
        *reinterpret_cast<s16x8*>(WkTB + (((size_t)(nblk * 32 + kt) * 1024 + c) << 3)) = h;
    }
}

// ---------------- kernel 3: fused GEMM 256x256, 1024 thr (16 waves of 64x64), 2-phase dbuf ----------------
__global__ __launch_bounds__(1024, 4) void gemm_e_kernel(
    const short* __restrict__ keyB,
    const short* __restrict__ WkTB,
    const float* __restrict__ qb,
    const float* __restrict__ v_mono, const float* __restrict__ v_chunk,
    float* __restrict__ e_ws /* [2][B_*T_] */) {
    __shared__ short As[2][1024 * 8];   // 32 KB: dbuf, 1024 swizzled 16B chunks
    __shared__ short Bs[2][1024 * 8];   // 32 KB
    int tid = threadIdx.x;
    int bid = blockIdx.x;
    int swz = (bid & 7) * 128 + (bid >> 3);   // XCD-aware (1024 % 8 == 0, bijective)
    int mt = swz >> 2;                        // 0..255
    int nt = swz & 3;                         // 0..3
    int mBase = mt * 256;
    int nBase = nt * 256;
    int lane = tid & 63;
    int wid = tid >> 6;                       // 0..15
    int wr = wid >> 2, wc = wid & 3;          // 4M x 4N waves, 64x64 each
    int col16 = lane & 15, g4 = lane >> 4;

    // staging: thread stages A chunk tid and B chunk tid (linear LDS dest)
    const short* pA = keyB + ((size_t)mt * 32 * 1024 + tid) * 8;
    const short* pB = WkTB + ((size_t)nt * 32 * 1024 + tid) * 8;
    int sAB = (wid * 64) * 8;          // wave-uniform LDS short-offset (lane x 16B implicit)

    // loop-invariant swizzled ds_read offsets (shorts)
    int aoff[4], boff[4];
#pragma unroll
    for (int m = 0; m < 4; ++m) {
        int row = wr * 64 + m * 16 + col16;           // 0..255
        aoff[m] = (row * 4 + (g4 ^ ((row >> 1) & 3))) * 8;
    }
#pragma unroll
    for (int n = 0; n < 4; ++n) {
        int row = wc * 64 + n * 16 + col16;           // 0..255
        boff[n] = (row * 4 + (g4 ^ ((row >> 1) & 3))) * 8;
    }

    f32x4 zero4 = {0.f, 0.f, 0.f, 0.f};
    f32x4 acc[4][4];
#pragma unroll
    for (int m = 0; m < 4; ++m)
#pragma unroll
        for (int n = 0; n < 4; ++n) acc[m][n] = zero4;

    // prologue: stage tile 0 into buf 0
    gload16(pA, &As[0][sAB]);
    gload16(pB, &Bs[0][sAB]);
    pA += 8192; pB += 8192;
    __syncthreads();

    int cur = 0;
    for (int kt = 0; kt < 31; ++kt) {
        int nxt = cur ^ 1;
        // prefetch next tile (overlaps with MFMA; drained by the barrier)
        gload16(pA, &As[nxt][sAB]);
        gload16(pB, &Bs[nxt][sAB]);
        pA += 8192; pB += 8192;
        // compute current tile
        s16x8 af[4], bfr[4];
#pragma unroll
        for (int m = 0; m < 4; ++m)
            af[m] = *reinterpret_cast<const s16x8*>(&As[cur][aoff[m]]);
#pragma unroll
        for (int n = 0; n < 4; ++n)
            bfr[n] = *reinterpret_cast<const s16x8*>(&Bs[cur][boff[n]]);
#pragma unroll
        for (int m = 0; m < 4; ++m)
#pragma unroll
            for (int n = 0; n < 4; ++n)
                acc[m][n] = __builtin_amdgcn_mfma_f32_16x16x32_bf16(af[m], bfr[n], acc[m][n], 0, 0, 0);
        __syncthreads();   // vmcnt drain: next buffer published, cur free
        cur = nxt;
    }
    {   // final tile
        s16x8 af[4], bfr[4];
#pragma unroll
        for (int m = 0; m < 4; ++m)
            af[m] = *reinterpret_cast<const s16x8*>(&As[cur][aoff[m]]);
#pragma unroll
        for (int n = 0; n < 4; ++n)
            bfr[n] = *reinterpret_cast<const s16x8*>(&Bs[cur][boff[n]]);
#pragma unroll
        for (int m = 0; m < 4; ++m)
#pragma unroll
            for (int n = 0; n < 4; ++n)
                acc[m][n] = __builtin_amdgcn_mfma_f32_16x16x32_bf16(af[m], bfr[n], acc[m][n], 0, 0, 0);
    }

    // epilogue: e[row] += sum_a v[a] * tanh(C[row][a] + qb[b][a])
    int bIdx = mBase >> 12;             // token row / 4096 (256 divides 4096)
    int matrix = nBase >> 9;            // 0=mono (nt 0,1), 1=chunk (nt 2,3)
    int aBase = (nBase & 511) + wc * 64 + col16;
    const float* qbRow = qb + (matrix * B_ + bIdx) * AD_;
    const float* vv = matrix ? v_chunk : v_mono;
    float* eArr = e_ws + matrix * (B_ * T_);
    float qcol[4], vcol[4];
#pragma unroll
    for (int n = 0; n < 4; ++n) {
        int a = aBase + n * 16;
        qcol[n] = qbRow[a];
        vcol[n] = vv[a];
    }
#pragma unroll
    for (int m = 0; m < 4; ++m) {
        float s0 = 0.f, s1 = 0.f, s2 = 0.f, s3 = 0.f;
#pragma unroll
        for (int n = 0; n < 4; ++n) {
            s0 += fast_tanh(acc[m][n][0] + qcol[n]) * vcol[n];
            s1 += fast_tanh(acc[m][n][1] + qcol[n]) * vcol[n];
            s2 += fast_tanh(acc[m][n][2] + qcol[n]) * vcol[n];
            s3 += fast_tanh(acc[m][n][3] + qcol[n]) * vcol[n];
        }
#pragma unroll
        for (int mask = 1; mask < 16; mask <<= 1) {
            s0 += __shfl_xor(s0, mask, 64);
            s1 += __shfl_xor(s1, mask, 64);
            s2 += __shfl_xor(s2, mask, 64);
            s3 += __shfl_xor(s3, mask, 64);
        }
        if (col16 == 0) {
            int rowB = mBase + wr * 64 + m * 16 + g4 * 4;
            atomicAdd(&eArr[rowB + 0], s0);
            atomicAdd(&eArr[rowB + 1], s1);
            atomicAdd(&eArr[rowB + 2], s2);
            atomicAdd(&eArr[rowB + 3], s3);
        }
    }
}

// ---------------- kernel 4: per-batch scan -> aw, beta ----------------
__global__ __launch_bounds__(256) void scan_kernel(
    const float* __restrict__ e_ws,
    const float* __restrict__ noise,
    const float* __restrict__ r_mono, const float* __restrict__ r_chunk,
    float* __restrict__ aw_out, float* __restrict__ beta_out) {
    __shared__ float s_aw[T_];
    __shared__ float s_sexp[T_];
    __shared__ float s_ad[T_];
    __shared__ float s_w[4];
    int b = blockIdx.x;
    int tid = threadIdx.x;
    int lane = tid & 63;
    int wid4 = tid >> 6;
    int t0 = tid * 16;
    const float* em = e_ws + b * T_;
    const float* ec = e_ws + B_ * T_ + b * T_;
    const float* nz = noise + b * T_;
    float rm = r_mono[0], rc = r_chunk[0];

    float pv[16], lp[16];
    float run = 0.f;
#pragma unroll
    for (int j = 0; j < 16; ++j) {
        float x = em[t0 + j] + rm + nz[t0 + j];
        float p = 1.f / (1.f + expf(-x));
        pv[j] = p;
        float om = fminf(fmaxf(1.f - p, 1e-10f), 1.f);
        lp[j] = run;
        run += logf(om);
    }
    float x = run;
#pragma unroll
    for (int off = 1; off < 64; off <<= 1) {
        float y = __shfl_up(x, off, 64);
        if (lane >= off) x += y;
    }
    if (lane == 63) s_w[wid4] = x;
    __syncthreads();
    float wbase = 0.f;
#pragma unroll
    for (int i = 0; i < 3; ++i) if (i < wid4) wbase += s_w[i];
    float base = 1.f + (wbase + x - run);
#pragma unroll
    for (int j = 0; j < 16; ++j) {
        float aw = pv[j] * expf(base + lp[j]);
        s_aw[t0 + j] = aw;
        aw_out[b * T_ + t0 + j] = aw;
    }
    float evs[16];
    float lmax = -INFINITY;
#pragma unroll
    for (int j = 0; j < 16; ++j) {
        float v = ec[t0 + j] + rc;
        evs[j] = v;
        lmax = fmaxf(lmax, v);
    }
#pragma unroll
    for (int off = 1; off < 64; off <<= 1)
        lmax = fmaxf(lmax, __shfl_xor(lmax, off, 64));
    __syncthreads();
    if (lane == 0) s_w[wid4] = lmax;
    __syncthreads();
    float mx = fmaxf(fmaxf(s_w[0], s_w[1]), fmaxf(s_w[2], s_w[3]));
#pragma unroll
    for (int j = 0; j < 16; ++j)
        s_sexp[t0 + j] = fmaxf(expf(evs[j] - mx), 1e-5f);
    __syncthreads();
#pragma unroll
    for (int j = 0; j < 16; ++j) {
        int t = t0 + j;
        int lo = t - 7; if (lo < 0) lo = 0;
        float d = 0.f;
        for (int i = lo; i <= t; ++i) d += s_sexp[i];
        s_ad[t] = s_aw[t] / d;
    }
    __syncthreads();
#pragma unroll
    for (int j = 0; j < 16; ++j) {
        int t = t0 + j;
        int hi = t + 7; if (hi > T_ - 1) hi = T_ - 1;
        float m2 = 0.f;
        for (int i = t; i <= hi; ++i) m2 += s_ad[i];
        beta_out[b * T_ + t] = s_sexp[t] * m2;
    }
}

// ---------------- kernel 5: cv[b][d] = sum_t beta[b][t]*value[b][t][d] ----------------
__global__ __launch_bounds__(256) void cv_kernel(
    const float* __restrict__ value,
    const float* __restrict__ beta,
    float* __restrict__ cv) {
    __shared__ float s_beta[128];
    int b = blockIdx.x;
    int tc = blockIdx.y;
    int tid = threadIdx.x;
    int t0 = tc * 128;
    if (tid < 128) s_beta[tid] = beta[b * T_ + t0 + tid];
    __syncthreads();
    int d0 = tid * 4;
    f32x4 acc = {0.f, 0.f, 0.f, 0.f};
    const float* vp = value + (size_t)(b * T_ + t0) * VD_ + d0;
#pragma unroll 4
    for (int i = 0; i < 128; ++i) {
        f32x4 v = *reinterpret_cast<const f32x4*>(vp + (size_t)i * VD_);
        float bt = s_beta[i];
        acc[0] += bt * v[0];
        acc[1] += bt * v[1];
        acc[2] += bt * v[2];
        acc[3] += bt * v[3];
    }
    atomicAdd(&cv[b * VD_ + d0 + 0], acc[0]);
    atomicAdd(&cv[b * VD_ + d0 + 1], acc[1]);
    atomicAdd(&cv[b * VD_ + d0 + 2], acc[2]);
    atomicAdd(&cv[b * VD_ + d0 + 3], acc[3]);
}

extern "C" void kernel_launch(void* const* d_in, const int* in_sizes, int n_in,
                              void* d_out, int out_size, void* d_ws, size_t ws_size,
                              hipStream_t stream) {
    const float* key      = (const float*)d_in[0];
    const float* value    = (const float*)d_in[1];
    const float* query    = (const float*)d_in[2];
    const float* noise    = (const float*)d_in[3];
    const float* Wk_mono  = (const float*)d_in[4];
    const float* b_mono   = (const float*)d_in[5];
    const float* Wq_mono  = (const float*)d_in[6];
    const float* Wk_chunk = (const float*)d_in[7];
    const float* b_chunk  = (const float*)d_in[8];
    const float* Wq_chunk = (const float*)d_in[9];
    const float* r_mono   = (const float*)d_in[10];
    const float* r_chunk  = (const float*)d_in[11];
    const float* v_mono   = (const float*)d_in[12];
    const float* v_chunk  = (const float*)d_in[13];
    float* out = (float*)d_out;   // [0,16384): cv ; [16384, 81920): aw

    char* ws = (char*)d_ws;
    size_t off = 0;
    float* e_ws = (float*)(ws + off); off += 2 * B_ * T_ * sizeof(float);      // 512 KB
    float* qb   = (float*)(ws + off); off += 2 * B_ * AD_ * sizeof(float);     // 64 KB
    short* WkTB = (short*)(ws + off); off += (size_t)KD_ * KD_ * 2;            // 2 MB (blocked+swizzled)
    float* beta = (float*)(ws + off); off += B_ * T_ * sizeof(float);          // 256 KB
    short* keyB = (short*)(ws + off);                                          // 134 MB (blocked+swizzled)

    hipMemsetAsync(e_ws, 0, 2 * B_ * T_ * sizeof(float), stream);
    hipMemsetAsync(out, 0, B_ * VD_ * sizeof(float), stream);

    qproj_kernel<<<dim3(16, 2, 8), 256, 0, stream>>>(query, Wq_mono, b_mono, Wq_chunk, b_chunk, qb);
    wtrans_kernel<<<dim3(32, 32), dim3(32, 8), 0, stream>>>(Wk_mono, Wk_chunk, WkTB);
    cvt_key_blk_kernel<<<4096, 256, 0, stream>>>(key, keyB);
    gemm_e_kernel<<<1024, 1024, 0, stream>>>(keyB, WkTB, qb, v_mono, v_chunk, e_ws);
    scan_kernel<<<16, 256, 0, stream>>>(e_ws, noise, r_mono, r_chunk, out + B_ * VD_, beta);
    cv_kernel<<<dim3(16, 32), 256, 0, stream>>>(value, beta, out);
}

// Round 10
// 360.894 us; speedup vs baseline: 1.4809x; 1.0443x over previous
//
#include <hip/hip_runtime.h>
#include <hip/hip_bf16.h>
#include <math.h>

#define B_   16
#define T_   4096
#define KD_  1024
#define AD_  512
#define VD_  1024

typedef float f32x4 __attribute__((ext_vector_type(4)));
typedef short s16x8 __attribute__((ext_vector_type(8)));

static __device__ __forceinline__ short f2bf(float f) {
    __hip_bfloat16 h = __float2bfloat16(f);
    return __builtin_bit_cast(short, h);
}

static __device__ __forceinline__ float fast_tanh(float x) {
    x = fminf(fmaxf(x, -15.f), 15.f);
    float e = __expf(2.f * x);
    return (e - 1.f) / (e + 1.f);
}

static __device__ __forceinline__ void gload16(const void* g, void* l) {
    __builtin_amdgcn_global_load_lds(
        (const __attribute__((address_space(1))) void*)(g),
        (__attribute__((address_space(3))) void*)(l), 16, 0, 0);
}

// Blocked operand layout, BK=64 K-tiles (16 of them), 256-row/col tiles:
//   keyB: [mt 256-rows][ktile 16][chunk c 2048][8 bf16], c = (r<<3)|(sub^(r&7)), r 0..255, sub 0..7
//   WkTB: [nt 256-cols][ktile 16][chunk c 2048][8 bf16], same formula
// LDS stays linear (global_load_lds); ds_read applies the same XOR -> 2-way (free).

// ---------------- kernel 0: key f32 -> bf16, blocked+swizzled ----------------
__global__ __launch_bounds__(256) void cvt_key_blk_kernel(
    const float* __restrict__ key, short* __restrict__ keyB) {
    const size_t nchunk = (size_t)B_ * T_ * KD_ / 8;
    size_t stride = (size_t)gridDim.x * 256;
    for (size_t g = (size_t)blockIdx.x * 256 + threadIdx.x; g < nchunk; g += stride) {
        const float* p = key + g * 8;          // contiguous read
        f32x4 f0 = *reinterpret_cast<const f32x4*>(p);
        f32x4 f1 = *reinterpret_cast<const f32x4*>(p + 4);
        s16x8 h;
        h[0] = f2bf(f0[0]); h[1] = f2bf(f0[1]); h[2] = f2bf(f0[2]); h[3] = f2bf(f0[3]);
        h[4] = f2bf(f1[0]); h[5] = f2bf(f1[1]); h[6] = f2bf(f1[2]); h[7] = f2bf(f1[3]);
        size_t m = g >> 7;
        int kc = (int)(g & 127);
        size_t mt = m >> 8;
        int r = (int)(m & 255);
        int ktile = kc >> 3;
        int sub = kc & 7;
        int c = (r << 3) | (sub ^ (r & 7));
        *reinterpret_cast<s16x8*>(keyB + (((mt * 16 + ktile) * 2048 + c) << 3)) = h;
    }
}

// ---------------- kernel 1: qb[mat][b][a] ----------------
__global__ __launch_bounds__(256) void qproj_kernel(
    const float* __restrict__ query,
    const float* __restrict__ Wq_mono, const float* __restrict__ b_mono,
    const float* __restrict__ Wq_chunk, const float* __restrict__ b_chunk,
    float* __restrict__ qb) {
    __shared__ float red[4][64];
    int b = blockIdx.x;
    int mat = blockIdx.y;
    int ac = blockIdx.z;
    const float* Wq = mat ? Wq_chunk : Wq_mono;
    const float* bb = mat ? b_chunk : b_mono;
    int al = threadIdx.x & 63;
    int dg = threadIdx.x >> 6;
    int a = ac * 64 + al;
    const float* q = query + b * KD_ + dg * 256;
    const float* wp = Wq + (size_t)(dg * 256) * AD_ + a;
    float s = 0.f;
#pragma unroll 4
    for (int d = 0; d < 256; ++d)
        s += q[d] * wp[(size_t)d * AD_];
    red[dg][al] = s;
    __syncthreads();
    if (dg == 0) {
        float t = red[0][al] + red[1][al] + red[2][al] + red[3][al];
        qb[(mat * B_ + b) * AD_ + a] = t + bb[a];
    }
}

// ---------------- kernel 2: weights -> bf16 blocked+swizzled WkTB ----------------
__global__ __launch_bounds__(256) void wtrans_kernel(
    const float* __restrict__ Wk_mono, const float* __restrict__ Wk_chunk,
    short* __restrict__ WkTB) {
    __shared__ float tile[32][33];
    int n0 = blockIdx.x * 32;
    int k0 = blockIdx.y * 32;
    int tx = threadIdx.x;
    int ty = threadIdx.y;
    int tid = ty * 32 + tx;
    const float* src;
    int nloc;
    if (n0 < 512) { src = Wk_mono;  nloc = n0; }
    else          { src = Wk_chunk; nloc = n0 - 512; }
#pragma unroll
    for (int i = 0; i < 4; ++i) {
        int k = ty + i * 8;
        tile[k][tx] = src[(size_t)(k0 + k) * AD_ + nloc + tx];
    }
    __syncthreads();
    if (tid < 128) {
        int rl = tid >> 2;      // local n (0..31)
        int sub2 = tid & 3;
        s16x8 h;
#pragma unroll
        for (int j = 0; j < 8; ++j)
            h[j] = f2bf(tile[sub2 * 8 + j][rl]);
        int n = n0 + rl;
        int nt = n >> 8;
        int rloc = n & 255;
        int ktile = k0 >> 6;
        int sub = ((k0 & 63) >> 3) + sub2;     // 0..7
        int c = (rloc << 3) | (sub ^ (rloc & 7));
        *reinterpret_cast<s16x8*>(WkTB + (((size_t)(nt * 16 + ktile) * 2048 + c) << 3)) = h;
    }
}

// ---------------- kernel 3: fused GEMM 256x256, BK=64, 8 waves, 8-phase counted-vmcnt ----------------
#define SBAR __builtin_amdgcn_sched_barrier(0)
#define BAR  do { SBAR; __builtin_amdgcn_s_barrier(); SBAR; } while (0)
#define VM6  asm volatile("s_waitcnt vmcnt(6)" ::: "memory")

#define STAGE_A(buf, kt, h) do { \
    const short* _g = aT + (((size_t)(kt) * 2048 + (h) * 1024) << 3); \
    gload16(_g + tid * 8,        &As[buf][(((h) * 1024 + wid * 64)) * 8]); \
    gload16(_g + (512 + tid) * 8, &As[buf][(((h) * 1024 + 512 + wid * 64)) * 8]); \
} while (0)

#define STAGE_B(buf, kt, h) do { \
    const short* _g = bT + (((size_t)(kt) * 2048 + (h) * 1024) << 3); \
    gload16(_g + tid * 8,        &Bs[buf][(((h) * 1024 + wid * 64)) * 8]); \
    gload16(_g + (512 + tid) * 8, &Bs[buf][(((h) * 1024 + 512 + wid * 64)) * 8]); \
} while (0)

#define DS_A(bb, mh) do { \
    _Pragma("unroll") \
    for (int _j = 0; _j < 4; ++_j) { \
        aR[_j][0] = *reinterpret_cast<const s16x8*>(&As[bb][aoff[(mh) * 4 + _j]]); \
        aR[_j][1] = *reinterpret_cast<const s16x8*>(&As[bb][aoff[(mh) * 4 + _j] ^ 32]); \
    } \
} while (0)

#define DS_B(bb, nh) do { \
    _Pragma("unroll") \
    for (int _j = 0; _j < 2; ++_j) { \
        bR[_j][0] = *reinterpret_cast<const s16x8*>(&Bs[bb][boff[(nh) * 2 + _j]]); \
        bR[_j][1] = *reinterpret_cast<const s16x8*>(&Bs[bb][boff[(nh) * 2 + _j] ^ 32]); \
    } \
} while (0)

#define MMA(mh, nh) do { \
    __builtin_amdgcn_s_setprio(1); \
    _Pragma("unroll") \
    for (int _j = 0; _j < 4; ++_j) \
    _Pragma("unroll") \
    for (int _n = 0; _n < 2; ++_n) { \
        acc[(mh) * 4 + _j][(nh) * 2 + _n] = __builtin_amdgcn_mfma_f32_16x16x32_bf16( \
            aR[_j][0], bR[_n][0], acc[(mh) * 4 + _j][(nh) * 2 + _n], 0, 0, 0); \
        acc[(mh) * 4 + _j][(nh) * 2 + _n] = __builtin_amdgcn_mfma_f32_16x16x32_bf16( \
            aR[_j][1], bR[_n][1], acc[(mh) * 4 + _j][(nh) * 2 + _n], 0, 0, 0); \
    } \
    __builtin_amdgcn_s_setprio(0); \
} while (0)

__global__ __launch_bounds__(512) void gemm_e_kernel(
    const short* __restrict__ keyB,
    const short* __restrict__ WkTB,
    const float* __restrict__ qb,
    const float* __restrict__ v_mono, const float* __restrict__ v_chunk,
    float* __restrict__ e_ws /* [2][B_*T_] */) {
    __shared__ short As[2][16384];   // 2 x 32 KB (256 rows x 64 K)
    __shared__ short Bs[2][16384];   // 2 x 32 KB
    int tid = threadIdx.x;
    int bid = blockIdx.x;
    int swz = (bid & 7) * 128 + (bid >> 3);   // XCD-aware (1024 % 8 == 0, bijective)
    int mt = swz >> 2;                        // 0..255
    int nt = swz & 3;                         // 0..3
    int mBase = mt * 256;
    int nBase = nt * 256;
    int lane = tid & 63;
    int wid = tid >> 6;                       // 0..7
    int wr = wid >> 2, wc = wid & 3;          // 2M x 4N waves; per-wave 128x64
    int col16 = lane & 15, g4 = lane >> 4;

    const short* aT = keyB + ((size_t)mt * 16 * 2048 << 3);
    const short* bT = WkTB + ((size_t)nt * 16 * 2048 << 3);

    // swizzled ds_read offsets (shorts); kk=1 -> ^32 (slot bit2 <-> sub bit2)
    int aoff[8], boff[4];
#pragma unroll
    for (int fi = 0; fi < 8; ++fi) {
        int row = wr * 128 + fi * 16 + col16;          // 0..255
        aoff[fi] = ((row << 3) | (g4 ^ (row & 7))) * 8;
    }
#pragma unroll
    for (int fj = 0; fj < 4; ++fj) {
        int col = wc * 64 + fj * 16 + col16;           // 0..255
        boff[fj] = ((col << 3) | (g4 ^ (col & 7))) * 8;
    }

    f32x4 acc[8][4];
#pragma unroll
    for (int i = 0; i < 8; ++i)
#pragma unroll
        for (int j = 0; j < 4; ++j) acc[i][j] = (f32x4){0.f, 0.f, 0.f, 0.f};

    s16x8 aR[4][2], bR[2][2];

    // prologue: 7 half-tiles: tile0 {A0,B0,B1,A1} -> buf0, tile1 {A0,B1,A1} -> buf1
    STAGE_A(0, 0, 0); STAGE_B(0, 0, 0); STAGE_B(0, 0, 1); STAGE_A(0, 0, 1);
    STAGE_A(1, 1, 0); STAGE_B(1, 1, 1); STAGE_A(1, 1, 1);
    VM6;   // tile0's 4 half-tiles landed; 3 in flight
    BAR;

    for (int it = 0; it < 8; ++it) {
        int t1 = 2 * it + 1;
        int t2 = 2 * it + 2 > 15 ? 15 : 2 * it + 2;
        int t3 = 2 * it + 3 > 15 ? 15 : 2 * it + 3;
        // P1: q(0,0) on buf0 | prefetch buf1.B0(t1)
        DS_A(0, 0); DS_B(0, 0);
        STAGE_B(1, t1, 0);
        BAR; MMA(0, 0); BAR;
        // P2: q(0,1) | prefetch buf0.A0(t2)
        DS_B(0, 1);
        STAGE_A(0, t2, 0);
        BAR; MMA(0, 1); BAR;
        // P3: q(1,1) | prefetch buf0.B1(t2)
        DS_A(0, 1);
        STAGE_B(0, t2, 1);
        BAR; MMA(1, 1); BAR;
        // P4: q(1,0) | prefetch buf0.A1(t2) | vmcnt(6): buf1(t1) complete
        DS_B(0, 0);
        STAGE_A(0, t2, 1);
        VM6;
        BAR; MMA(1, 0); BAR;
        // P5: q(0,0) on buf1 | prefetch buf0.B0(t2)
        DS_A(1, 0); DS_B(1, 0);
        STAGE_B(0, t2, 0);
        BAR; MMA(0, 0); BAR;
        // P6: q(0,1) | prefetch buf1.A0(t3)
        DS_B(1, 1);
        STAGE_A(1, t3, 0);
        BAR; MMA(0, 1); BAR;
        // P7: q(1,1) | prefetch buf1.B1(t3)
        DS_A(1, 1);
        STAGE_B(1, t3, 1);
        BAR; MMA(1, 1); BAR;
        // P8: q(1,0) | prefetch buf1.A1(t3) | vmcnt(6): buf0(t2) complete
        DS_B(1, 0);
        STAGE_A(1, t3, 1);
        VM6;
        BAR; MMA(1, 0); BAR;
    }

    asm volatile("s_waitcnt vmcnt(0)" ::: "memory");

    // epilogue: e[row] += sum_a v[a] * tanh(C[row][a] + qb[b][a])
    int bIdx = mBase >> 12;
    int matrix = nBase >> 9;            // nt 0,1 -> mono; 2,3 -> chunk
    int aBase = (nBase & 511) + wc * 64 + col16;
    const float* qbRow = qb + (matrix * B_ + bIdx) * AD_;
    const float* vv = matrix ? v_chunk : v_mono;
    float* eArr = e_ws + matrix * (B_ * T_);
    float qcol[4], vcol[4];
#pragma unroll
    for (int n = 0; n < 4; ++n) {
        int a = aBase + n * 16;
        qcol[n] = qbRow[a];
        vcol[n] = vv[a];
    }
#pragma unroll
    for (int fi = 0; fi < 8; ++fi) {
        float s0 = 0.f, s1 = 0.f, s2 = 0.f, s3 = 0.f;
#pragma unroll
        for (int n = 0; n < 4; ++n) {
            s0 += fast_tanh(acc[fi][n][0] + qcol[n]) * vcol[n];
            s1 += fast_tanh(acc[fi][n][1] + qcol[n]) * vcol[n];
            s2 += fast_tanh(acc[fi][n][2] + qcol[n]) * vcol[n];
            s3 += fast_tanh(acc[fi][n][3] + qcol[n]) * vcol[n];
        }
#pragma unroll
        for (int mask = 1; mask < 16; mask <<= 1) {
            s0 += __shfl_xor(s0, mask, 64);
            s1 += __shfl_xor(s1, mask, 64);
            s2 += __shfl_xor(s2, mask, 64);
            s3 += __shfl_xor(s3, mask, 64);
        }
        if (col16 == 0) {
            int rowB = mBase + wr * 128 + fi * 16 + g4 * 4;
            atomicAdd(&eArr[rowB + 0], s0);
            atomicAdd(&eArr[rowB + 1], s1);
            atomicAdd(&eArr[rowB + 2], s2);
            atomicAdd(&eArr[rowB + 3], s3);
        }
    }
}

// ---------------- kernel 4: per-batch scan -> aw, beta ----------------
__global__ __launch_bounds__(256) void scan_kernel(
    const float* __restrict__ e_ws,
    const float* __restrict__ noise,
    const float* __restrict__ r_mono, const float* __restrict__ r_chunk,
    float* __restrict__ aw_out, float* __restrict__ beta_out) {
    __shared__ float s_aw[T_];
    __shared__ float s_sexp[T_];
    __shared__ float s_ad[T_];
    __shared__ float s_w[4];
    int b = blockIdx.x;
    int tid = threadIdx.x;
    int lane = tid & 63;
    int wid4 = tid >> 6;
    int t0 = tid * 16;
    const float* em = e_ws + b * T_;
    const float* ec = e_ws + B_ * T_ + b * T_;
    const float* nz = noise + b * T_;
    float rm = r_mono[0], rc = r_chunk[0];

    float pv[16], lp[16];
    float run = 0.f;
#pragma unroll
    for (int j = 0; j < 16; ++j) {
        float x = em[t0 + j] + rm + nz[t0 + j];
        float p = 1.f / (1.f + expf(-x));
        pv[j] = p;
        float om = fminf(fmaxf(1.f - p, 1e-10f), 1.f);
        lp[j] = run;
        run += logf(om);
    }
    float x = run;
#pragma unroll
    for (int off = 1; off < 64; off <<= 1) {
        float y = __shfl_up(x, off, 64);
        if (lane >= off) x += y;
    }
    if (lane == 63) s_w[wid4] = x;
    __syncthreads();
    float wbase = 0.f;
#pragma unroll
    for (int i = 0; i < 3; ++i) if (i < wid4) wbase += s_w[i];
    float base = 1.f + (wbase + x - run);
#pragma unroll
    for (int j = 0; j < 16; ++j) {
        float aw = pv[j] * expf(base + lp[j]);
        s_aw[t0 + j] = aw;
        aw_out[b * T_ + t0 + j] = aw;
    }
    float evs[16];
    float lmax = -INFINITY;
#pragma unroll
    for (int j = 0; j < 16; ++j) {
        float v = ec[t0 + j] + rc;
        evs[j] = v;
        lmax = fmaxf(lmax, v);
    }
#pragma unroll
    for (int off = 1; off < 64; off <<= 1)
        lmax = fmaxf(lmax, __shfl_xor(lmax, off, 64));
    __syncthreads();
    if (lane == 0) s_w[wid4] = lmax;
    __syncthreads();
    float mx = fmaxf(fmaxf(s_w[0], s_w[1]), fmaxf(s_w[2], s_w[3]));
#pragma unroll
    for (int j = 0; j < 16; ++j)
        s_sexp[t0 + j] = fmaxf(expf(evs[j] - mx), 1e-5f);
    __syncthreads();
#pragma unroll
    for (int j = 0; j < 16; ++j) {
        int t = t0 + j;
        int lo = t - 7; if (lo < 0) lo = 0;
        float d = 0.f;
        for (int i = lo; i <= t; ++i) d += s_sexp[i];
        s_ad[t] = s_aw[t] / d;
    }
    __syncthreads();
#pragma unroll
    for (int j = 0; j < 16; ++j) {
        int t = t0 + j;
        int hi = t + 7; if (hi > T_ - 1) hi = T_ - 1;
        float m2 = 0.f;
        for (int i = t; i <= hi; ++i) m2 += s_ad[i];
        beta_out[b * T_ + t] = s_sexp[t] * m2;
    }
}

// ---------------- kernel 5: cv[b][d] = sum_t beta[b][t]*value[b][t][d] ----------------
__global__ __launch_bounds__(256) void cv_kernel(
    const float* __restrict__ value,
    const float* __restrict__ beta,
    float* __restrict__ cv) {
    __shared__ float s_beta[128];
    int b = blockIdx.x;
    int tc = blockIdx.y;
    int tid = threadIdx.x;
    int t0 = tc * 128;
    if (tid < 128) s_beta[tid] = beta[b * T_ + t0 + tid];
    __syncthreads();
    int d0 = tid * 4;
    f32x4 acc = {0.f, 0.f, 0.f, 0.f};
    const float* vp = value + (size_t)(b * T_ + t0) * VD_ + d0;
#pragma unroll 4
    for (int i = 0; i < 128; ++i) {
        f32x4 v = *reinterpret_cast<const f32x4*>(vp + (size_t)i * VD_);
        float bt = s_beta[i];
        acc[0] += bt * v[0];
        acc[1] += bt * v[1];
        acc[2] += bt * v[2];
        acc[3] += bt * v[3];
    }
    atomicAdd(&cv[b * VD_ + d0 + 0], acc[0]);
    atomicAdd(&cv[b * VD_ + d0 + 1], acc[1]);
    atomicAdd(&cv[b * VD_ + d0 + 2], acc[2]);
    atomicAdd(&cv[b * VD_ + d0 + 3], acc[3]);
}

extern "C" void kernel_launch(void* const* d_in, const int* in_sizes, int n_in,
                              void* d_out, int out_size, void* d_ws, size_t ws_size,
                              hipStream_t stream) {
    const float* key      = (const float*)d_in[0];
    const float* value    = (const float*)d_in[1];
    const float* query    = (const float*)d_in[2];
    const float* noise    = (const float*)d_in[3];
    const float* Wk_mono  = (const float*)d_in[4];
    const float* b_mono   = (const float*)d_in[5];
    const float* Wq_mono  = (const float*)d_in[6];
    const float* Wk_chunk = (const float*)d_in[7];
    const float* b_chunk  = (const float*)d_in[8];
    const float* Wq_chunk = (const float*)d_in[9];
    const float* r_mono   = (const float*)d_in[10];
    const float* r_chunk  = (const float*)d_in[11];
    const float* v_mono   = (const float*)d_in[12];
    const float* v_chunk  = (const float*)d_in[13];
    float* out = (float*)d_out;   // [0,16384): cv ; [16384, 81920): aw

    char* ws = (char*)d_ws;
    size_t off = 0;
    float* e_ws = (float*)(ws + off); off += 2 * B_ * T_ * sizeof(float);      // 512 KB
    float* qb   = (float*)(ws + off); off += 2 * B_ * AD_ * sizeof(float);     // 64 KB
    short* WkTB = (short*)(ws + off); off += (size_t)KD_ * KD_ * 2;            // 2 MB
    float* beta = (float*)(ws + off); off += B_ * T_ * sizeof(float);          // 256 KB
    short* keyB = (short*)(ws + off);                                          // 134 MB

    hipMemsetAsync(e_ws, 0, 2 * B_ * T_ * sizeof(float), stream);
    hipMemsetAsync(out, 0, B_ * VD_ * sizeof(float), stream);

    qproj_kernel<<<dim3(16, 2, 8), 256, 0, stream>>>(query, Wq_mono, b_mono, Wq_chunk, b_chunk, qb);
    wtrans_kernel<<<dim3(32, 32), dim3(32, 8), 0, stream>>>(Wk_mono, Wk_chunk, WkTB);
    cvt_key_blk_kernel<<<4096, 256, 0, stream>>>(key, keyB);
    gemm_e_kernel<<<1024, 512, 0, stream>>>(keyB, WkTB, qb, v_mono, v_chunk, e_ws);
    scan_kernel<<<16, 256, 0, stream>>>(e_ws, noise, r_mono, r_chunk, out + B_ * VD_, beta);
    cv_kernel<<<dim3(16, 32), 256, 0, stream>>>(value, beta, out);
}

// Round 11
// 340.716 us; speedup vs baseline: 1.5686x; 1.0592x over previous
//
#include <hip/hip_runtime.h>
#include <hip/hip_bf16.h>
#include <math.h>

#define B_   16
#define T_   4096
#define KD_  1024
#define AD_  512
#define VD_  1024

typedef float f32x4 __attribute__((ext_vector_type(4)));
typedef short s16x8 __attribute__((ext_vector_type(8)));

static __device__ __forceinline__ short f2bf(float f) {
    __hip_bfloat16 h = __float2bfloat16(f);
    return __builtin_bit_cast(short, h);
}

static __device__ __forceinline__ float fast_tanh(float x) {
    x = fminf(fmaxf(x, -15.f), 15.f);
    float e = __expf(2.f * x);
    return (e - 1.f) / (e + 1.f);
}

static __device__ __forceinline__ void gload16(const void* g, void* l) {
    __builtin_amdgcn_global_load_lds(
        (const __attribute__((address_space(1))) void*)(g),
        (__attribute__((address_space(3))) void*)(l), 16, 0, 0);
}

// Blocked operand layout, BK=64 K-tiles (16 of them), 256-row/col tiles:
//   keyB: [mt 256-rows][ktile 16][chunk c 2048][8 bf16], c = (r<<3)|(sub^(r&7)), r 0..255, sub 0..7
//   WkTB: [nt 256-cols][ktile 16][chunk c 2048][8 bf16], same formula
// LDS stays linear (global_load_lds); ds_read applies the same XOR -> 2-way (free).

// ---------------- fused prep kernel: cvt(4096) | wtrans(1024) | qproj(256) | memset(144) ----------------
__global__ __launch_bounds__(256) void prep_kernel(
    const float* __restrict__ key, short* __restrict__ keyB,
    const float* __restrict__ Wk_mono, const float* __restrict__ Wk_chunk,
    short* __restrict__ WkTB,
    const float* __restrict__ query,
    const float* __restrict__ Wq_mono, const float* __restrict__ b_mono,
    const float* __restrict__ Wq_chunk, const float* __restrict__ b_chunk,
    float* __restrict__ qb,
    float* __restrict__ e_ws, float* __restrict__ outzero) {
    int bid = blockIdx.x;
    int tid = threadIdx.x;

    if (bid < 4096) {
        // ---- key f32 -> bf16, blocked+swizzled ----
        const size_t nchunk = (size_t)B_ * T_ * KD_ / 8;
        size_t stride = (size_t)4096 * 256;
        for (size_t g = (size_t)bid * 256 + tid; g < nchunk; g += stride) {
            const float* p = key + g * 8;
            f32x4 f0 = *reinterpret_cast<const f32x4*>(p);
            f32x4 f1 = *reinterpret_cast<const f32x4*>(p + 4);
            s16x8 h;
            h[0] = f2bf(f0[0]); h[1] = f2bf(f0[1]); h[2] = f2bf(f0[2]); h[3] = f2bf(f0[3]);
            h[4] = f2bf(f1[0]); h[5] = f2bf(f1[1]); h[6] = f2bf(f1[2]); h[7] = f2bf(f1[3]);
            size_t m = g >> 7;
            int kc = (int)(g & 127);
            size_t mt = m >> 8;
            int r = (int)(m & 255);
            int ktile = kc >> 3;
            int sub = kc & 7;
            int c = (r << 3) | (sub ^ (r & 7));
            *reinterpret_cast<s16x8*>(keyB + (((mt * 16 + ktile) * 2048 + c) << 3)) = h;
        }
    } else if (bid < 5120) {
        // ---- weights -> bf16 blocked+swizzled WkTB ----
        __shared__ float tile[32][33];
        int wbid = bid - 4096;
        int n0 = (wbid & 31) * 32;
        int k0 = (wbid >> 5) * 32;
        int tx = tid & 31;
        int ty = tid >> 5;
        const float* src;
        int nloc;
        if (n0 < 512) { src = Wk_mono;  nloc = n0; }
        else          { src = Wk_chunk; nloc = n0 - 512; }
#pragma unroll
        for (int i = 0; i < 4; ++i) {
            int k = ty + i * 8;
            tile[k][tx] = src[(size_t)(k0 + k) * AD_ + nloc + tx];
        }
        __syncthreads();
        if (tid < 128) {
            int rl = tid >> 2;
            int sub2 = tid & 3;
            s16x8 h;
#pragma unroll
            for (int j = 0; j < 8; ++j)
                h[j] = f2bf(tile[sub2 * 8 + j][rl]);
            int n = n0 + rl;
            int nt = n >> 8;
            int rloc = n & 255;
            int ktile = k0 >> 6;
            int sub = ((k0 & 63) >> 3) + sub2;
            int c = (rloc << 3) | (sub ^ (rloc & 7));
            *reinterpret_cast<s16x8*>(WkTB + (((size_t)(nt * 16 + ktile) * 2048 + c) << 3)) = h;
        }
    } else if (bid < 5376) {
        // ---- qproj ----
        __shared__ float red[4][64];
        int qbid = bid - 5120;
        int b = qbid & 15;
        int mat = (qbid >> 4) & 1;
        int ac = qbid >> 5;
        const float* Wq = mat ? Wq_chunk : Wq_mono;
        const float* bb = mat ? b_chunk : b_mono;
        int al = tid & 63;
        int dg = tid >> 6;
        int a = ac * 64 + al;
        const float* q = query + b * KD_ + dg * 256;
        const float* wp = Wq + (size_t)(dg * 256) * AD_ + a;
        float s = 0.f;
#pragma unroll 4
        for (int d = 0; d < 256; ++d)
            s += q[d] * wp[(size_t)d * AD_];
        red[dg][al] = s;
        __syncthreads();
        if (dg == 0) {
            float t = red[0][al] + red[1][al] + red[2][al] + red[3][al];
            qb[(mat * B_ + b) * AD_ + a] = t + bb[a];
        }
    } else {
        // ---- zero e_ws (128 blocks x 4KB) then out (16 blocks x 4KB) ----
        int zbid = bid - 5376;
        f32x4 z = {0.f, 0.f, 0.f, 0.f};
        if (zbid < 128) {
            float* dst = e_ws + (size_t)zbid * 1024 + tid * 4;
            *reinterpret_cast<f32x4*>(dst) = z;
        } else {
            float* dst = outzero + (size_t)(zbid - 128) * 1024 + tid * 4;
            *reinterpret_cast<f32x4*>(dst) = z;
        }
    }
}

// ---------------- kernel 3: fused GEMM 256x256, BK=64, 8 waves, 8-phase counted-vmcnt ----------------
#define SBAR __builtin_amdgcn_sched_barrier(0)
#define BAR  do { SBAR; __builtin_amdgcn_s_barrier(); SBAR; } while (0)
#define VM6  asm volatile("s_waitcnt vmcnt(6)" ::: "memory")

#define STAGE_A(buf, kt, h) do { \
    const short* _g = aT + (((size_t)(kt) * 2048 + (h) * 1024) << 3); \
    gload16(_g + tid * 8,        &As[buf][(((h) * 1024 + wid * 64)) * 8]); \
    gload16(_g + (512 + tid) * 8, &As[buf][(((h) * 1024 + 512 + wid * 64)) * 8]); \
} while (0)

#define STAGE_B(buf, kt, h) do { \
    const short* _g = bT + (((size_t)(kt) * 2048 + (h) * 1024) << 3); \
    gload16(_g + tid * 8,        &Bs[buf][(((h) * 1024 + wid * 64)) * 8]); \
    gload16(_g + (512 + tid) * 8, &Bs[buf][(((h) * 1024 + 512 + wid * 64)) * 8]); \
} while (0)

#define DS_A(bb, mh) do { \
    _Pragma("unroll") \
    for (int _j = 0; _j < 4; ++_j) { \
        aR[_j][0] = *reinterpret_cast<const s16x8*>(&As[bb][aoff[(mh) * 4 + _j]]); \
        aR[_j][1] = *reinterpret_cast<const s16x8*>(&As[bb][aoff[(mh) * 4 + _j] ^ 32]); \
    } \
} while (0)

#define DS_B(bb, nh) do { \
    _Pragma("unroll") \
    for (int _j = 0; _j < 2; ++_j) { \
        bR[_j][0] = *reinterpret_cast<const s16x8*>(&Bs[bb][boff[(nh) * 2 + _j]]); \
        bR[_j][1] = *reinterpret_cast<const s16x8*>(&Bs[bb][boff[(nh) * 2 + _j] ^ 32]); \
    } \
} while (0)

#define MMA(mh, nh) do { \
    __builtin_amdgcn_s_setprio(1); \
    _Pragma("unroll") \
    for (int _j = 0; _j < 4; ++_j) \
    _Pragma("unroll") \
    for (int _n = 0; _n < 2; ++_n) { \
        acc[(mh) * 4 + _j][(nh) * 2 + _n] = __builtin_amdgcn_mfma_f32_16x16x32_bf16( \
            aR[_j][0], bR[_n][0], acc[(mh) * 4 + _j][(nh) * 2 + _n], 0, 0, 0); \
        acc[(mh) * 4 + _j][(nh) * 2 + _n] = __builtin_amdgcn_mfma_f32_16x16x32_bf16( \
            aR[_j][1], bR[_n][1], acc[(mh) * 4 + _j][(nh) * 2 + _n], 0, 0, 0); \
    } \
    __builtin_amdgcn_s_setprio(0); \
} while (0)

__global__ __launch_bounds__(512) void gemm_e_kernel(
    const short* __restrict__ keyB,
    const short* __restrict__ WkTB,
    const float* __restrict__ qb,
    const float* __restrict__ v_mono, const float* __restrict__ v_chunk,
    float* __restrict__ e_ws /* [2][B_*T_] */) {
    __shared__ short As[2][16384];   // 2 x 32 KB (256 rows x 64 K)
    __shared__ short Bs[2][16384];   // 2 x 32 KB
    int tid = threadIdx.x;
    int bid = blockIdx.x;
    int swz = (bid & 7) * 128 + (bid >> 3);   // XCD-aware (1024 % 8 == 0, bijective)
    int mt = swz >> 2;                        // 0..255
    int nt = swz & 3;                         // 0..3
    int mBase = mt * 256;
    int nBase = nt * 256;
    int lane = tid & 63;
    int wid = tid >> 6;                       // 0..7
    int wr = wid >> 2, wc = wid & 3;          // 2M x 4N waves; per-wave 128x64
    int col16 = lane & 15, g4 = lane >> 4;

    const short* aT = keyB + ((size_t)mt * 16 * 2048 << 3);
    const short* bT = WkTB + ((size_t)nt * 16 * 2048 << 3);

    // swizzled ds_read offsets (shorts); kk=1 -> ^32 (slot bit2 <-> sub bit2)
    int aoff[8], boff[4];
#pragma unroll
    for (int fi = 0; fi < 8; ++fi) {
        int row = wr * 128 + fi * 16 + col16;          // 0..255
        aoff[fi] = ((row << 3) | (g4 ^ (row & 7))) * 8;
    }
#pragma unroll
    for (int fj = 0; fj < 4; ++fj) {
        int col = wc * 64 + fj * 16 + col16;           // 0..255
        boff[fj] = ((col << 3) | (g4 ^ (col & 7))) * 8;
    }

    f32x4 acc[8][4];
#pragma unroll
    for (int i = 0; i < 8; ++i)
#pragma unroll
        for (int j = 0; j < 4; ++j) acc[i][j] = (f32x4){0.f, 0.f, 0.f, 0.f};

    s16x8 aR[4][2], bR[2][2];

    // prologue: 7 half-tiles: tile0 {A0,B0,B1,A1} -> buf0, tile1 {A0,B1,A1} -> buf1
    STAGE_A(0, 0, 0); STAGE_B(0, 0, 0); STAGE_B(0, 0, 1); STAGE_A(0, 0, 1);
    STAGE_A(1, 1, 0); STAGE_B(1, 1, 1); STAGE_A(1, 1, 1);
    VM6;   // tile0's 4 half-tiles landed; 3 in flight
    BAR;

    for (int it = 0; it < 8; ++it) {
        int t1 = 2 * it + 1;
        int t2 = 2 * it + 2 > 15 ? 15 : 2 * it + 2;
        int t3 = 2 * it + 3 > 15 ? 15 : 2 * it + 3;
        // P1: q(0,0) on buf0 | prefetch buf1.B0(t1)
        DS_A(0, 0); DS_B(0, 0);
        STAGE_B(1, t1, 0);
        BAR; MMA(0, 0); BAR;
        // P2: q(0,1) | prefetch buf0.A0(t2)
        DS_B(0, 1);
        STAGE_A(0, t2, 0);
        BAR; MMA(0, 1); BAR;
        // P3: q(1,1) | prefetch buf0.B1(t2)
        DS_A(0, 1);
        STAGE_B(0, t2, 1);
        BAR; MMA(1, 1); BAR;
        // P4: q(1,0) | prefetch buf0.A1(t2) | vmcnt(6): buf1(t1) complete
        DS_B(0, 0);
        STAGE_A(0, t2, 1);
        VM6;
        BAR; MMA(1, 0); BAR;
        // P5: q(0,0) on buf1 | prefetch buf0.B0(t2)
        DS_A(1, 0); DS_B(1, 0);
        STAGE_B(0, t2, 0);
        BAR; MMA(0, 0); BAR;
        // P6: q(0,1) | prefetch buf1.A0(t3)
        DS_B(1, 1);
        STAGE_A(1, t3, 0);
        BAR; MMA(0, 1); BAR;
        // P7: q(1,1) | prefetch buf1.B1(t3)
        DS_A(1, 1);
        STAGE_B(1, t3, 1);
        BAR; MMA(1, 1); BAR;
        // P8: q(1,0) | prefetch buf1.A1(t3) | vmcnt(6): buf0(t2) complete
        DS_B(1, 0);
        STAGE_A(1, t3, 1);
        VM6;
        BAR; MMA(1, 0); BAR;
    }

    asm volatile("s_waitcnt vmcnt(0)" ::: "memory");

    // epilogue: e[row] += sum_a v[a] * tanh(C[row][a] + qb[b][a])
    int bIdx = mBase >> 12;
    int matrix = nBase >> 9;            // nt 0,1 -> mono; 2,3 -> chunk
    int aBase = (nBase & 511) + wc * 64 + col16;
    const float* qbRow = qb + (matrix * B_ + bIdx) * AD_;
    const float* vv = matrix ? v_chunk : v_mono;
    float* eArr = e_ws + matrix * (B_ * T_);
    float qcol[4], vcol[4];
#pragma unroll
    for (int n = 0; n < 4; ++n) {
        int a = aBase + n * 16;
        qcol[n] = qbRow[a];
        vcol[n] = vv[a];
    }
#pragma unroll
    for (int fi = 0; fi < 8; ++fi) {
        float s0 = 0.f, s1 = 0.f, s2 = 0.f, s3 = 0.f;
#pragma unroll
        for (int n = 0; n < 4; ++n) {
            s0 += fast_tanh(acc[fi][n][0] + qcol[n]) * vcol[n];
            s1 += fast_tanh(acc[fi][n][1] + qcol[n]) * vcol[n];
            s2 += fast_tanh(acc[fi][n][2] + qcol[n]) * vcol[n];
            s3 += fast_tanh(acc[fi][n][3] + qcol[n]) * vcol[n];
        }
#pragma unroll
        for (int mask = 1; mask < 16; mask <<= 1) {
            s0 += __shfl_xor(s0, mask, 64);
            s1 += __shfl_xor(s1, mask, 64);
            s2 += __shfl_xor(s2, mask, 64);
            s3 += __shfl_xor(s3, mask, 64);
        }
        if (col16 == 0) {
            int rowB = mBase + wr * 128 + fi * 16 + g4 * 4;
            atomicAdd(&eArr[rowB + 0], s0);
            atomicAdd(&eArr[rowB + 1], s1);
            atomicAdd(&eArr[rowB + 2], s2);
            atomicAdd(&eArr[rowB + 3], s3);
        }
    }
}

// ---------------- kernel 4: per-batch scan -> aw, beta ----------------
__global__ __launch_bounds__(256) void scan_kernel(
    const float* __restrict__ e_ws,
    const float* __restrict__ noise,
    const float* __restrict__ r_mono, const float* __restrict__ r_chunk,
    float* __restrict__ aw_out, float* __restrict__ beta_out) {
    __shared__ float s_aw[T_];
    __shared__ float s_sexp[T_];
    __shared__ float s_ad[T_];
    __shared__ float s_w[4];
    int b = blockIdx.x;
    int tid = threadIdx.x;
    int lane = tid & 63;
    int wid4 = tid >> 6;
    int t0 = tid * 16;
    const float* em = e_ws + b * T_;
    const float* ec = e_ws + B_ * T_ + b * T_;
    const float* nz = noise + b * T_;
    float rm = r_mono[0], rc = r_chunk[0];

    float pv[16], lp[16];
    float run = 0.f;
#pragma unroll
    for (int j = 0; j < 16; ++j) {
        float x = em[t0 + j] + rm + nz[t0 + j];
        float p = 1.f / (1.f + expf(-x));
        pv[j] = p;
        float om = fminf(fmaxf(1.f - p, 1e-10f), 1.f);
        lp[j] = run;
        run += logf(om);
    }
    float x = run;
#pragma unroll
    for (int off = 1; off < 64; off <<= 1) {
        float y = __shfl_up(x, off, 64);
        if (lane >= off) x += y;
    }
    if (lane == 63) s_w[wid4] = x;
    __syncthreads();
    float wbase = 0.f;
#pragma unroll
    for (int i = 0; i < 3; ++i) if (i < wid4) wbase += s_w[i];
    float base = 1.f + (wbase + x - run);
#pragma unroll
    for (int j = 0; j < 16; ++j) {
        float aw = pv[j] * expf(base + lp[j]);
        s_aw[t0 + j] = aw;
        aw_out[b * T_ + t0 + j] = aw;
    }
    float evs[16];
    float lmax = -INFINITY;
#pragma unroll
    for (int j = 0; j < 16; ++j) {
        float v = ec[t0 + j] + rc;
        evs[j] = v;
        lmax = fmaxf(lmax, v);
    }
#pragma unroll
    for (int off = 1; off < 64; off <<= 1)
        lmax = fmaxf(lmax, __shfl_xor(lmax, off, 64));
    __syncthreads();
    if (lane == 0) s_w[wid4] = lmax;
    __syncthreads();
    float mx = fmaxf(fmaxf(s_w[0], s_w[1]), fmaxf(s_w[2], s_w[3]));
#pragma unroll
    for (int j = 0; j < 16; ++j)
        s_sexp[t0 + j] = fmaxf(expf(evs[j] - mx), 1e-5f);
    __syncthreads();
#pragma unroll
    for (int j = 0; j < 16; ++j) {
        int t = t0 + j;
        int lo = t - 7; if (lo < 0) lo = 0;
        float d = 0.f;
        for (int i = lo; i <= t; ++i) d += s_sexp[i];
        s_ad[t] = s_aw[t] / d;
    }
    __syncthreads();
#pragma unroll
    for (int j = 0; j < 16; ++j) {
        int t = t0 + j;
        int hi = t + 7; if (hi > T_ - 1) hi = T_ - 1;
        float m2 = 0.f;
        for (int i = t; i <= hi; ++i) m2 += s_ad[i];
        beta_out[b * T_ + t] = s_sexp[t] * m2;
    }
}

// ---------------- kernel 5: cv[b][d] = sum_t beta[b][t]*value[b][t][d] ----------------
__global__ __launch_bounds__(256) void cv_kernel(
    const float* __restrict__ value,
    const float* __restrict__ beta,
    float* __restrict__ cv) {
    __shared__ float s_beta[128];
    int b = blockIdx.x;
    int tc = blockIdx.y;
    int tid = threadIdx.x;
    int t0 = tc * 128;
    if (tid < 128) s_beta[tid] = beta[b * T_ + t0 + tid];
    __syncthreads();
    int d0 = tid * 4;
    f32x4 acc = {0.f, 0.f, 0.f, 0.f};
    const float* vp = value + (size_t)(b * T_ + t0) * VD_ + d0;
#pragma unroll 4
    for (int i = 0; i < 128; ++i) {
        f32x4 v = *reinterpret_cast<const f32x4*>(vp + (size_t)i * VD_);
        float bt = s_beta[i];
        acc[0] += bt * v[0];
        acc[1] += bt * v[1];
        acc[2] += bt * v[2];
        acc[3] += bt * v[3];
    }
    atomicAdd(&cv[b * VD_ + d0 + 0], acc[0]);
    atomicAdd(&cv[b * VD_ + d0 + 1], acc[1]);
    atomicAdd(&cv[b * VD_ + d0 + 2], acc[2]);
    atomicAdd(&cv[b * VD_ + d0 + 3], acc[3]);
}

extern "C" void kernel_launch(void* const* d_in, const int* in_sizes, int n_in,
                              void* d_out, int out_size, void* d_ws, size_t ws_size,
                              hipStream_t stream) {
    const float* key      = (const float*)d_in[0];
    const float* value    = (const float*)d_in[1];
    const float* query    = (const float*)d_in[2];
    const float* noise    = (const float*)d_in[3];
    const float* Wk_mono  = (const float*)d_in[4];
    const float* b_mono   = (const float*)d_in[5];
    const float* Wq_mono  = (const float*)d_in[6];
    const float* Wk_chunk = (const float*)d_in[7];
    const float* b_chunk  = (const float*)d_in[8];
    const float* Wq_chunk = (const float*)d_in[9];
    const float* r_mono   = (const float*)d_in[10];
    const float* r_chunk  = (const float*)d_in[11];
    const float* v_mono   = (const float*)d_in[12];
    const float* v_chunk  = (const float*)d_in[13];
    float* out = (float*)d_out;   // [0,16384): cv ; [16384, 81920): aw

    char* ws = (char*)d_ws;
    size_t off = 0;
    float* e_ws = (float*)(ws + off); off += 2 * B_ * T_ * sizeof(float);      // 512 KB
    float* qb   = (float*)(ws + off); off += 2 * B_ * AD_ * sizeof(float);     // 64 KB
    short* WkTB = (short*)(ws + off); off += (size_t)KD_ * KD_ * 2;            // 2 MB
    float* beta = (float*)(ws + off); off += B_ * T_ * sizeof(float);          // 256 KB
    short* keyB = (short*)(ws + off);                                          // 134 MB

    prep_kernel<<<5520, 256, 0, stream>>>(key, keyB, Wk_mono, Wk_chunk, WkTB,
                                          query, Wq_mono, b_mono, Wq_chunk, b_chunk, qb,
                                          e_ws, out);
    gemm_e_kernel<<<1024, 512, 0, stream>>>(keyB, WkTB, qb, v_mono, v_chunk, e_ws);
    scan_kernel<<<16, 256, 0, stream>>>(e_ws, noise, r_mono, r_chunk, out + B_ * VD_, beta);
    cv_kernel<<<dim3(16, 32), 256, 0, stream>>>(value, beta, out);
}